// Round 1
// 570.885 us; speedup vs baseline: 1.3433x; 1.3433x over previous
//
#include <hip/hip_runtime.h>
#include <hip/hip_bf16.h>
#include <math.h>

#define NPTS 1000000
#define DIM 64
#define HID 64
#define NPATCH 4096
#define BM 128
#define LDH 72  // padded row stride (bf16 elems): 144B rows, 16B-aligned, bank-friendly

typedef float f32x4 __attribute__((ext_vector_type(4)));
typedef __bf16 bf16x8 __attribute__((ext_vector_type(8)));
typedef __bf16 bf16x4 __attribute__((ext_vector_type(4)));

// -------- Pass 1: per-block LDS accumulation, then global atomic flush ------
#define PB_BLOCKS 64
#define PB_PTS (NPTS / PB_BLOCKS)  // 15625 exactly

__global__ __launch_bounds__(256) void patch_partial(const float* __restrict__ coord,
                                                     const int* __restrict__ ids,
                                                     float* __restrict__ acc4) {
    __shared__ float lacc[NPATCH * 4];  // 64 KB
    for (int j = threadIdx.x; j < NPATCH * 4; j += 256) lacc[j] = 0.0f;
    __syncthreads();
    const int start = blockIdx.x * PB_PTS;
    const int end = start + PB_PTS;
    for (int i = start + threadIdx.x; i < end; i += 256) {
        int p = ids[i];
        float cx = coord[3 * i + 0];
        float cy = coord[3 * i + 1];
        float cz = coord[3 * i + 2];
        atomicAdd(&lacc[4 * p + 0], cx);
        atomicAdd(&lacc[4 * p + 1], cy);
        atomicAdd(&lacc[4 * p + 2], cz);
        atomicAdd(&lacc[4 * p + 3], 1.0f);
    }
    __syncthreads();
    for (int j = threadIdx.x; j < NPATCH * 4; j += 256)
        atomicAdd(&acc4[j], lacc[j]);
}

// -------- Pass 2: fused MLP + residual + depthwise + pointwise + LayerNorm ---
// GEMMs computed TRANSPOSED (D = W^T * h^T) so each lane's 4 acc regs are 4
// consecutive channels of one point -> float4 global loads/stores for x and out.
__global__ __launch_bounds__(256, 4) void cpe_main(
    const float* __restrict__ x, const float* __restrict__ coord,
    const int* __restrict__ ids,
    const float* __restrict__ W1, const float* __restrict__ b1,
    const float* __restrict__ W2, const float* __restrict__ b2,
    const float* __restrict__ dww, const float* __restrict__ dwb,
    const float* __restrict__ pwW, const float* __restrict__ pwb,
    const float* __restrict__ lng, const float* __restrict__ lnb,
    const float* __restrict__ acc4, float* __restrict__ out) {

    __shared__ __align__(16) __bf16 sW2t[64 * LDH];  // [n][k] = W2[k][n]
    __shared__ __align__(16) __bf16 sPWt[64 * LDH];  // [n][k] = pwW[k][n]
    __shared__ __align__(16) __bf16 sHY[BM * LDH];   // h then reused for y
    __shared__ float sW1[3 * 64];
    __shared__ __align__(16) float sb1[64], sb2[64], sdww[64], sdwb[64],
                                   spwb[64], slng[64], slnb[64];

    const int tid = threadIdx.x;
    const int lane = tid & 63;
    const int wave = tid >> 6;
    const int block0 = blockIdx.x * BM;
    const int q = lane >> 4;   // quad 0..3 -> channel sub-block
    const int ln = lane & 15;  // lane-in-quad -> point index within 16-tile

    // ---- prefetch x in D-fragment layout: point row, 4 consecutive channels ----
    const int prow0 = wave * 32 + ln;
    f32x4 xv[2][4];
    #pragma unroll
    for (int m = 0; m < 2; ++m) {
        int gp = block0 + prow0 + m * 16;
        const float* xr = x + (size_t)gp * 64 + q * 4;
        #pragma unroll
        for (int t = 0; t < 4; ++t)
            xv[m][t] = (gp < NPTS) ? *(const f32x4*)(xr + t * 16)
                                   : (f32x4){0.f, 0.f, 0.f, 0.f};
    }

    // ---- stage params + transposed bf16 weights ----
    if (tid < 192) sW1[tid] = W1[tid];
    if (tid < 64) {
        sb1[tid] = b1[tid];  sb2[tid] = b2[tid];
        sdww[tid] = dww[tid]; sdwb[tid] = dwb[tid];
        spwb[tid] = pwb[tid]; slng[tid] = lng[tid]; slnb[tid] = lnb[tid];
    }
    for (int e = tid; e < 64 * 64; e += 256) {
        int k = e >> 6, n = e & 63;
        sW2t[n * LDH + k] = (__bf16)W2[e];
        sPWt[n * LDH + k] = (__bf16)pwW[e];
    }
    __syncthreads();

    // ---- fp32 MLP 3->64 with exact-erf GELU, write h (bf16), row-major ----
    {
        int p = tid & (BM - 1);
        int half = tid >> 7;  // 0 or 1: which 32 hidden units
        int gp = block0 + p;
        float d0 = 0.f, d1 = 0.f, d2 = 0.f;
        if (gp < NPTS) {
            int pid = ids[gp];
            float4 a = ((const float4*)acc4)[pid];
            float invc = 1.0f / fmaxf(a.w, 1.0f);
            d0 = coord[3 * gp + 0] - a.x * invc;
            d1 = coord[3 * gp + 1] - a.y * invc;
            d2 = coord[3 * gp + 2] - a.z * invc;
        }
        #pragma unroll
        for (int j0 = 0; j0 < 32; j0 += 8) {
            bf16x8 pack;
            #pragma unroll
            for (int u = 0; u < 8; ++u) {
                int j = half * 32 + j0 + u;
                float v = sb1[j] + d0 * sW1[j] + d1 * sW1[64 + j] + d2 * sW1[128 + j];
                v = 0.5f * v * (1.0f + erff(v * 0.70710678118654752f));
                pack[u] = (__bf16)v;
            }
            *(bf16x8*)&sHY[p * LDH + half * 32 + j0] = pack;
        }
    }
    __syncthreads();

    // ---- GEMM1 (transposed): acc[m][t][r] = pos[point prow0+m*16][chan t*16+q*4+r] ----
    f32x4 acc[2][4];
    #pragma unroll
    for (int m = 0; m < 2; ++m)
        #pragma unroll
        for (int t = 0; t < 4; ++t)
            acc[m][t] = (f32x4){0.f, 0.f, 0.f, 0.f};

    #pragma unroll
    for (int ks = 0; ks < 2; ++ks) {
        bf16x8 hw[2], wf[4];
        #pragma unroll
        for (int m = 0; m < 2; ++m)
            hw[m] = *(const bf16x8*)&sHY[(prow0 + m * 16) * LDH + ks * 32 + q * 8];
        #pragma unroll
        for (int t = 0; t < 4; ++t)
            wf[t] = *(const bf16x8*)&sW2t[(t * 16 + ln) * LDH + ks * 32 + q * 8];
        #pragma unroll
        for (int m = 0; m < 2; ++m)
            #pragma unroll
            for (int t = 0; t < 4; ++t)
                acc[m][t] = __builtin_amdgcn_mfma_f32_16x16x32_bf16(wf[t], hw[m], acc[m][t], 0, 0, 0);
    }
    __syncthreads();  // all waves done reading sHY (h)

    // ---- epilogue1: out = x + pos + b2; y = out*dww + dwb -> bf16 to sHY ----
    #pragma unroll
    for (int m = 0; m < 2; ++m) {
        #pragma unroll
        for (int t = 0; t < 4; ++t) {
            int c0 = t * 16 + q * 4;
            f32x4 o = xv[m][t] + acc[m][t] + *(const f32x4*)&sb2[c0];
            f32x4 y = o * *(const f32x4*)&sdww[c0] + *(const f32x4*)&sdwb[c0];
            bf16x4 yb;
            #pragma unroll
            for (int j = 0; j < 4; ++j) yb[j] = (__bf16)y[j];
            *(bf16x4*)&sHY[(prow0 + m * 16) * LDH + c0] = yb;
        }
    }
    __syncthreads();

    // ---- GEMM2 (transposed): o = (y @ pw_W)^T fragments ----
    #pragma unroll
    for (int m = 0; m < 2; ++m)
        #pragma unroll
        for (int t = 0; t < 4; ++t)
            acc[m][t] = (f32x4){0.f, 0.f, 0.f, 0.f};

    #pragma unroll
    for (int ks = 0; ks < 2; ++ks) {
        bf16x8 yw[2], wf[4];
        #pragma unroll
        for (int m = 0; m < 2; ++m)
            yw[m] = *(const bf16x8*)&sHY[(prow0 + m * 16) * LDH + ks * 32 + q * 8];
        #pragma unroll
        for (int t = 0; t < 4; ++t)
            wf[t] = *(const bf16x8*)&sPWt[(t * 16 + ln) * LDH + ks * 32 + q * 8];
        #pragma unroll
        for (int m = 0; m < 2; ++m)
            #pragma unroll
            for (int t = 0; t < 4; ++t)
                acc[m][t] = __builtin_amdgcn_mfma_f32_16x16x32_bf16(wf[t], yw[m], acc[m][t], 0, 0, 0);
    }

    // ---- LayerNorm: lane holds 16 chans of its point; reduce across q-groups ----
    #pragma unroll
    for (int m = 0; m < 2; ++m) {
        int gp = block0 + prow0 + m * 16;
        f32x4 v[4];
        float s = 0.f, ss = 0.f;
        #pragma unroll
        for (int t = 0; t < 4; ++t) {
            int c0 = t * 16 + q * 4;
            v[t] = acc[m][t] + *(const f32x4*)&spwb[c0];
            #pragma unroll
            for (int j = 0; j < 4; ++j) { s += v[t][j]; ss += v[t][j] * v[t][j]; }
        }
        s += __shfl_xor(s, 16);  s += __shfl_xor(s, 32);
        ss += __shfl_xor(ss, 16); ss += __shfl_xor(ss, 32);
        float mu = s * (1.0f / 64.0f);
        float rs = rsqrtf(ss * (1.0f / 64.0f) - mu * mu + 1e-5f);
        if (gp < NPTS) {
            float* op = out + (size_t)gp * 64;
            #pragma unroll
            for (int t = 0; t < 4; ++t) {
                int c0 = t * 16 + q * 4;
                f32x4 g = *(const f32x4*)&slng[c0];
                f32x4 b = *(const f32x4*)&slnb[c0];
                f32x4 o = (v[t] - mu) * rs * g + b;
                *(f32x4*)(op + c0) = o;
            }
        }
    }
}

extern "C" void kernel_launch(void* const* d_in, const int* in_sizes, int n_in,
                              void* d_out, int out_size, void* d_ws, size_t ws_size,
                              hipStream_t stream) {
    const float* x     = (const float*)d_in[0];
    const float* coord = (const float*)d_in[1];
    const int*   ids   = (const int*)d_in[2];
    const float* W1    = (const float*)d_in[3];
    const float* b1    = (const float*)d_in[4];
    const float* W2    = (const float*)d_in[5];
    const float* b2    = (const float*)d_in[6];
    const float* dww   = (const float*)d_in[7];
    const float* dwb   = (const float*)d_in[8];
    const float* pwW   = (const float*)d_in[9];
    const float* pwb   = (const float*)d_in[10];
    const float* lng   = (const float*)d_in[11];
    const float* lnb   = (const float*)d_in[12];
    float* outp = (float*)d_out;
    float* acc4 = (float*)d_ws;

    hipMemsetAsync(d_ws, 0, NPATCH * 4 * sizeof(float), stream);
    patch_partial<<<PB_BLOCKS, 256, 0, stream>>>(coord, ids, acc4);
    cpe_main<<<(NPTS + BM - 1) / BM, 256, 0, stream>>>(
        x, coord, ids, W1, b1, W2, b2, dww, dwb, pwW, pwb, lng, lnb, acc4, outp);
}

// Round 3
// 527.843 us; speedup vs baseline: 1.4528x; 1.0815x over previous
//
#include <hip/hip_runtime.h>
#include <hip/hip_bf16.h>
#include <math.h>

#define NPTS 1000000
#define NPATCH 4096
#define BM 128

typedef float f32x4 __attribute__((ext_vector_type(4)));
typedef __bf16 bf16x8 __attribute__((ext_vector_type(8)));
typedef __bf16 bf16x4 __attribute__((ext_vector_type(4)));

#define PB_BLOCKS 250
#define PB_PTS (NPTS / PB_BLOCKS)  // 4000 exactly

// sH plane stride (bf16): BM*8 data + 16 pad -> per-granule bank shift of 8
#define SPLANE (BM * 8 + 16)  // 1040

// ---- module-scope scratch: NO dependence on d_ws / ws_size ------------------
__device__ __align__(16) float  g_acc4[NPATCH * 4];            // 64 KB
__device__ __align__(16) __bf16 g_w2f[4096];                   // fragment-major
__device__ __align__(16) __bf16 g_pwf[4096];
__device__ __align__(16) float  g_part[PB_BLOCKS * NPATCH * 4];  // 16 MB

// -------- one-time: W2 / pwW -> bf16 fragment-major --------------------------
// dst[((ks*4+t)*64 + lane)*8 + j] = src[(ks*32 + (lane>>4)*8 + j)*64 + t*16 + (lane&15)]
__global__ __launch_bounds__(256) void transpose_w(const float* __restrict__ W2,
                                                   const float* __restrict__ pwW) {
    const float* src = (blockIdx.x == 0) ? W2 : pwW;
    __bf16* dst = (blockIdx.x == 0) ? g_w2f : g_pwf;
    for (int e = threadIdx.x; e < 4096; e += 256) {
        int j = e & 7;
        int lane = (e >> 3) & 63;
        int ft = e >> 9;              // ks*4 + t
        int ks = ft >> 2, t = ft & 3;
        int q = lane >> 4, ln = lane & 15;
        dst[e] = (__bf16)src[(ks * 32 + q * 8 + j) * 64 + t * 16 + ln];
    }
}

// -------- patch sums: LDS histogram (plane-major) -> non-atomic partials -----
__global__ __launch_bounds__(256) void patch_partial(const float* __restrict__ coord,
                                                     const int* __restrict__ ids) {
    __shared__ float lacc[4 * NPATCH];  // [comp][patch]
    for (int j = threadIdx.x; j < 4 * NPATCH; j += 256) lacc[j] = 0.0f;
    __syncthreads();
    const int start = blockIdx.x * PB_PTS;
    const int end = start + PB_PTS;
    for (int i = start + threadIdx.x; i < end; i += 256) {
        int p = ids[i];
        atomicAdd(&lacc[0 * NPATCH + p], coord[3 * i + 0]);
        atomicAdd(&lacc[1 * NPATCH + p], coord[3 * i + 1]);
        atomicAdd(&lacc[2 * NPATCH + p], coord[3 * i + 2]);
        atomicAdd(&lacc[3 * NPATCH + p], 1.0f);
    }
    __syncthreads();
    // dump interleaved {sx,sy,sz,cnt} per patch -> fully coalesced reduce reads
    float* dst = g_part + (size_t)blockIdx.x * 4 * NPATCH;
    for (int j = threadIdx.x; j < 4 * NPATCH; j += 256) {
        int p = j >> 2, c = j & 3;
        dst[j] = lacc[c * NPATCH + p];
    }
}

// -------- reduce partials -> interleaved acc4 --------------------------------
__global__ __launch_bounds__(256) void patch_reduce() {
    int j = blockIdx.x * 256 + threadIdx.x;  // 0..16383
    float s = 0.0f;
    #pragma unroll 10
    for (int k = 0; k < PB_BLOCKS; ++k)
        s += g_part[(size_t)k * 4 * NPATCH + j];
    g_acc4[j] = s;
}

// -------- main fused kernel --------------------------------------------------
// Transposed MFMA (D = W^T * h^T): lane's 4 acc regs = 4 consecutive channels
// of one point -> float4 x/out traffic. Weight fragments: coalesced global
// (fragment-major bf16, L1-resident). sH granule-major + plane pad -> ~no
// bank conflicts. LDS ~20.7KB -> 7 blocks/CU.
__global__ __launch_bounds__(256, 8) void cpe_main(
    const float* __restrict__ x, const float* __restrict__ coord,
    const int* __restrict__ ids,
    const float* __restrict__ W1, const float* __restrict__ b1,
    const float* __restrict__ b2,
    const float* __restrict__ dww, const float* __restrict__ dwb,
    const float* __restrict__ pwb,
    const float* __restrict__ lng, const float* __restrict__ lnb,
    float* __restrict__ out) {

    __shared__ __align__(16) __bf16 sH[8 * SPLANE];   // granule-major, padded
    __shared__ __align__(16) float scoord[BM * 3];
    __shared__ float sW1[192];
    __shared__ __align__(16) float sb1[64], sb2[64], sdww[64], sdwb[64],
                                   spwb[64], slng[64], slnb[64];

    const int tid = threadIdx.x;
    const int lane = tid & 63;
    const int wave = tid >> 6;
    const int block0 = blockIdx.x * BM;
    const int q = lane >> 4;
    const int ln = lane & 15;
    const int prow0 = wave * 32 + ln;

    // ---- stage params + coord tile ----
    if (tid < 192) sW1[tid] = W1[tid];
    if (tid < 64) {
        sb1[tid] = b1[tid];  sb2[tid] = b2[tid];
        sdww[tid] = dww[tid]; sdwb[tid] = dwb[tid];
        spwb[tid] = pwb[tid]; slng[tid] = lng[tid]; slnb[tid] = lnb[tid];
    }
    if (tid < 96) {
        int g4 = (block0 * 3) / 4 + tid;
        f32x4 c = (g4 < (NPTS * 3) / 4) ? ((const f32x4*)coord)[g4]
                                        : (f32x4){0.f, 0.f, 0.f, 0.f};
        *(f32x4*)&scoord[tid * 4] = c;
    }
    __syncthreads();

    // ---- fp32 MLP 3->64, exact-erf GELU, write h (bf16) granule-major ----
    {
        int p = tid & (BM - 1);
        int half = tid >> 7;
        int gp = block0 + p;
        float d0 = 0.f, d1 = 0.f, d2 = 0.f;
        if (gp < NPTS) {
            int pid = ids[gp];
            float4 a = ((const float4*)g_acc4)[pid];
            float invc = 1.0f / fmaxf(a.w, 1.0f);
            d0 = scoord[3 * p + 0] - a.x * invc;
            d1 = scoord[3 * p + 1] - a.y * invc;
            d2 = scoord[3 * p + 2] - a.z * invc;
        }
        #pragma unroll
        for (int j0 = 0; j0 < 32; j0 += 8) {
            bf16x8 pack;
            #pragma unroll
            for (int u = 0; u < 8; ++u) {
                int j = half * 32 + j0 + u;
                float v = sb1[j] + d0 * sW1[j] + d1 * sW1[64 + j] + d2 * sW1[128 + j];
                v = 0.5f * v * (1.0f + erff(v * 0.70710678118654752f));
                pack[u] = (__bf16)v;
            }
            int g = half * 4 + (j0 >> 3);
            *(bf16x8*)&sH[g * SPLANE + p * 8] = pack;
        }
    }
    __syncthreads();

    // ---- GEMM1: acc[m][t][r] = pos[prow0+m*16][t*16+q*4+r] ----
    f32x4 acc[2][4];
    #pragma unroll
    for (int m = 0; m < 2; ++m)
        #pragma unroll
        for (int t = 0; t < 4; ++t)
            acc[m][t] = (f32x4){0.f, 0.f, 0.f, 0.f};

    #pragma unroll
    for (int ks = 0; ks < 2; ++ks) {
        bf16x8 hw[2], wf[4];
        #pragma unroll
        for (int m = 0; m < 2; ++m)
            hw[m] = *(const bf16x8*)&sH[(ks * 4 + q) * SPLANE + (prow0 + m * 16) * 8];
        #pragma unroll
        for (int t = 0; t < 4; ++t)
            wf[t] = *(const bf16x8*)&g_w2f[((ks * 4 + t) * 64 + lane) * 8];
        #pragma unroll
        for (int m = 0; m < 2; ++m)
            #pragma unroll
            for (int t = 0; t < 4; ++t)
                acc[m][t] = __builtin_amdgcn_mfma_f32_16x16x32_bf16(wf[t], hw[m], acc[m][t], 0, 0, 0);
    }

    // ---- x load: issued between GEMM1 and barrier; compiler may sink ----
    f32x4 xv[2][4];
    #pragma unroll
    for (int m = 0; m < 2; ++m) {
        int gp = block0 + prow0 + m * 16;
        const float* xr = x + (size_t)gp * 64 + q * 4;
        #pragma unroll
        for (int t = 0; t < 4; ++t)
            xv[m][t] = (gp < NPTS) ? *(const f32x4*)(xr + t * 16)
                                   : (f32x4){0.f, 0.f, 0.f, 0.f};
    }
    __syncthreads();  // all waves done reading sH (h)

    // ---- epilogue1: out = x + pos + b2; y = out*dww + dwb -> bf16 to sH ----
    #pragma unroll
    for (int m = 0; m < 2; ++m) {
        #pragma unroll
        for (int t = 0; t < 4; ++t) {
            int c0 = t * 16 + q * 4;
            f32x4 o = xv[m][t] + acc[m][t] + *(const f32x4*)&sb2[c0];
            f32x4 y = o * *(const f32x4*)&sdww[c0] + *(const f32x4*)&sdwb[c0];
            bf16x4 yb;
            #pragma unroll
            for (int j = 0; j < 4; ++j) yb[j] = (__bf16)y[j];
            int g = 2 * t + (q >> 1);
            *(bf16x4*)&sH[g * SPLANE + (prow0 + m * 16) * 8 + (q & 1) * 4] = yb;
        }
    }
    __syncthreads();

    // ---- GEMM2: o = (y @ pw_W)^T fragments ----
    #pragma unroll
    for (int m = 0; m < 2; ++m)
        #pragma unroll
        for (int t = 0; t < 4; ++t)
            acc[m][t] = (f32x4){0.f, 0.f, 0.f, 0.f};

    #pragma unroll
    for (int ks = 0; ks < 2; ++ks) {
        bf16x8 yw[2], wf[4];
        #pragma unroll
        for (int m = 0; m < 2; ++m)
            yw[m] = *(const bf16x8*)&sH[(ks * 4 + q) * SPLANE + (prow0 + m * 16) * 8];
        #pragma unroll
        for (int t = 0; t < 4; ++t)
            wf[t] = *(const bf16x8*)&g_pwf[((ks * 4 + t) * 64 + lane) * 8];
        #pragma unroll
        for (int m = 0; m < 2; ++m)
            #pragma unroll
            for (int t = 0; t < 4; ++t)
                acc[m][t] = __builtin_amdgcn_mfma_f32_16x16x32_bf16(wf[t], yw[m], acc[m][t], 0, 0, 0);
    }

    // ---- LayerNorm in registers; reduce across quads via shfl ----
    #pragma unroll
    for (int m = 0; m < 2; ++m) {
        int gp = block0 + prow0 + m * 16;
        f32x4 v[4];
        float s = 0.f, ss = 0.f;
        #pragma unroll
        for (int t = 0; t < 4; ++t) {
            int c0 = t * 16 + q * 4;
            v[t] = acc[m][t] + *(const f32x4*)&spwb[c0];
            #pragma unroll
            for (int j = 0; j < 4; ++j) { s += v[t][j]; ss += v[t][j] * v[t][j]; }
        }
        s += __shfl_xor(s, 16);  s += __shfl_xor(s, 32);
        ss += __shfl_xor(ss, 16); ss += __shfl_xor(ss, 32);
        float mu = s * (1.0f / 64.0f);
        float rs = rsqrtf(ss * (1.0f / 64.0f) - mu * mu + 1e-5f);
        if (gp < NPTS) {
            float* op = out + (size_t)gp * 64;
            #pragma unroll
            for (int t = 0; t < 4; ++t) {
                int c0 = t * 16 + q * 4;
                f32x4 g = *(const f32x4*)&slng[c0];
                f32x4 b = *(const f32x4*)&slnb[c0];
                f32x4 o = (v[t] - mu) * rs * g + b;
                __builtin_nontemporal_store(o, (f32x4*)(op + c0));
            }
        }
    }
}

extern "C" void kernel_launch(void* const* d_in, const int* in_sizes, int n_in,
                              void* d_out, int out_size, void* d_ws, size_t ws_size,
                              hipStream_t stream) {
    const float* x     = (const float*)d_in[0];
    const float* coord = (const float*)d_in[1];
    const int*   ids   = (const int*)d_in[2];
    const float* W1    = (const float*)d_in[3];
    const float* b1    = (const float*)d_in[4];
    const float* W2    = (const float*)d_in[5];
    const float* b2    = (const float*)d_in[6];
    const float* dww   = (const float*)d_in[7];
    const float* dwb   = (const float*)d_in[8];
    const float* pwW   = (const float*)d_in[9];
    const float* pwb   = (const float*)d_in[10];
    const float* lng   = (const float*)d_in[11];
    const float* lnb   = (const float*)d_in[12];
    float* outp = (float*)d_out;
    (void)d_ws; (void)ws_size;

    transpose_w<<<2, 256, 0, stream>>>(W2, pwW);
    patch_partial<<<PB_BLOCKS, 256, 0, stream>>>(coord, ids);
    patch_reduce<<<NPATCH * 4 / 256, 256, 0, stream>>>();
    cpe_main<<<(NPTS + BM - 1) / BM, 256, 0, stream>>>(
        x, coord, ids, W1, b1, b2, dww, dwb, pwb, lng, lnb, outp);
}